// Round 1
// baseline (620.289 us; speedup 1.0000x reference)
//
#include <hip/hip_runtime.h>
#include <hip/hip_bf16.h>

typedef __attribute__((ext_vector_type(4))) float f4v;
typedef __attribute__((ext_vector_type(8))) short bf8v;

// ---- problem constants ----
// x: (2,192,32,32,32) f32; mask: (2,1,8,8,8); dw_w: (192,1,7,7,7); HID=768
#define NPOS 32768            // 32*32*32
#define CCH  192
#define HID  768

// ---- workspace layout (bytes) ----
#define WS_XT   ((size_t)0)           // 2*32768*192*4 = 50,331,648  x transposed channels-last
#define WS_WT   ((size_t)50331648)    // 343*192*4     = 263,424     dw_w transposed [tap][c]
#define WS_B1F  ((size_t)50595072)    // 294,912       w1 bf16 B-frag swizzled
#define WS_B2F  ((size_t)50889984)    // 294,912       w2 bf16 B-frag swizzled
#define WS_LNA  ((size_t)51184896)    // 1024*12288*2  = 25,165,824  LN output bf16 A-frag swizzled
// total: 76,350,720 bytes

__device__ inline unsigned short f2bf(float f){
  unsigned int u = __float_as_uint(f);
  u += 0x7FFFu + ((u >> 16) & 1u);      // RNE
  return (unsigned short)(u >> 16);
}

__device__ inline float gelu_f(float x){
  // tanh-approx GELU; |err| ~3e-4 abs, well inside the 2%-of-max budget
  float u = 0.7978845608028654f * x * fmaf(0.044715f, x*x, 1.0f);
  float e = __expf(2.0f*u);
  float th = __fdividef(e - 1.0f, e + 1.0f);
  return 0.5f*x*(1.0f + th);
}

// ---------------------------------------------------------------------------
// Kernel 1: transpose x (B,C,D,H,W) -> xT[b][z*1024+y*32+x][c]  (channels-last)
// One block per (b,z,y) row: 2048 blocks x 256 threads.
// ---------------------------------------------------------------------------
__global__ __launch_bounds__(256) void transpose_x_kernel(
    const float* __restrict__ x, float* __restrict__ xT)
{
  __shared__ float t[32*193];
  int bid = blockIdx.x;
  int b = bid >> 10, z = (bid >> 5) & 31, y = bid & 31;
  int tid = threadIdx.x;
  int xx = tid & 31, ch0 = tid >> 5;
  size_t base_in = (size_t)b*CCH*NPOS + (size_t)z*1024 + y*32;
  for (int it = 0; it < 24; ++it) {
    int c = it*8 + ch0;
    t[xx*193 + c] = x[base_in + (size_t)c*NPOS + xx];
  }
  __syncthreads();
  size_t base_out = ((size_t)b*NPOS + z*1024 + y*32) * CCH;
  #pragma unroll
  for (int p = 0; p < 6; ++p) {
    int f4i = p*256 + tid;          // 0..1535
    int flat = f4i*4;               // 0..6143
    int xo = flat / 192;
    int cc = flat - xo*192;
    f4v v;
    v.x = t[xo*193 + cc + 0];
    v.y = t[xo*193 + cc + 1];
    v.z = t[xo*193 + cc + 2];
    v.w = t[xo*193 + cc + 3];
    *(f4v*)(xT + base_out + flat) = v;
  }
}

// ---------------------------------------------------------------------------
// Kernel 2: weight prep. w_t[tap][c]; w1/w2 -> bf16 MFMA-B-fragment order.
// B-frag (16x16x32): element (k,n) -> lane=((k%32)/8)*16+(n%16), byte j=k%8.
// ---------------------------------------------------------------------------
__global__ __launch_bounds__(256) void prep_w_kernel(
    const float* __restrict__ dw_w, const float* __restrict__ w1,
    const float* __restrict__ w2, float* __restrict__ w_t,
    unsigned short* __restrict__ b1f, unsigned short* __restrict__ b2f)
{
  int gid = blockIdx.x*256 + threadIdx.x;
  if (gid < 343*192) {
    int tap = gid / 192, c = gid - tap*192;
    w_t[gid] = dw_w[c*343 + tap];
  } else if (gid < 343*192 + 18432) {
    int fi = gid - 343*192;               // frag-lane id for w1 (C=192 x HID=768)
    int lane = fi & 63, fr = fi >> 6;
    int nt = fr / 6, ks = fr - nt*6;      // ntile 0..47, kstep 0..5
    int n  = nt*16 + (lane & 15);
    int kb = ks*32 + (lane >> 4)*8;
    #pragma unroll
    for (int j = 0; j < 8; ++j) b1f[fi*8 + j] = f2bf(w1[(kb+j)*HID + n]);
  } else if (gid < 343*192 + 36864) {
    int fi = gid - 343*192 - 18432;       // frag-lane id for w2 (HID=768 x C=192)
    int lane = fi & 63, fr = fi >> 6;
    int nt = fr / 24, ks = fr - nt*24;    // ntile 0..11, kstep 0..23
    int n  = nt*16 + (lane & 15);
    int kb = ks*32 + (lane >> 4)*8;
    #pragma unroll
    for (int j = 0; j < 8; ++j) b2f[fi*8 + j] = f2bf(w2[(kb+j)*CCH + n]);
  }
}

// ---------------------------------------------------------------------------
// Kernel 3: depthwise 7x7x7 conv + bias + LayerNorm, per active 4^3 cell.
// 1024 blocks (b,cell) x 768 threads. wave=(dz,cgroup), lane=channel.
// Inactive cells: zero-fill d_out tile. Active: write LN result (bf16) in
// MFMA A-fragment order to lnA.
// ---------------------------------------------------------------------------
__global__ __launch_bounds__(768, 3) void conv_ln_kernel(
    const float* __restrict__ xT, const float* __restrict__ w_t,
    const float* __restrict__ dw_b, const float* __restrict__ ln_w,
    const float* __restrict__ ln_b, const int* __restrict__ mask,
    unsigned short* __restrict__ lnA, float* __restrict__ out)
{
  int bid = blockIdx.x;
  int b = bid >> 9, cell = bid & 511;
  int cz = cell >> 6, cy = (cell >> 3) & 7, cx = cell & 7;
  int z0 = cz*4, y0 = cy*4, x0 = cx*4;
  int tid = threadIdx.x, wave = tid >> 6, lane = tid & 63;
  int dz = wave & 3, cg = wave >> 2;

  if (mask[bid] == 0) {
    f4v z4 = {0.f, 0.f, 0.f, 0.f};
    #pragma unroll
    for (int p = 0; p < 4; ++p) {
      int i4 = tid + 768*p;               // 0..3071
      int c = i4 >> 4, rem = i4 & 15;
      int dzz = rem >> 2, dyy = rem & 3;
      size_t off = ((size_t)b*CCH + c)*NPOS + (z0+dzz)*1024 + (y0+dyy)*32 + x0;
      *(f4v*)(out + off) = z4;
    }
    return;
  }

  int c = cg*64 + lane;
  const float* xb = xT + (size_t)b*NPOS*CCH;
  float acc[16];
  #pragma unroll
  for (int i = 0; i < 16; ++i) acc[i] = 0.f;

  for (int kz = 0; kz < 7; ++kz) {
    int zi = z0 + dz + kz - 3;
    if ((unsigned)zi >= 32u) continue;    // wave-uniform
    float wreg[49];
    #pragma unroll
    for (int i = 0; i < 49; ++i) wreg[i] = w_t[(kz*49 + i)*CCH + c];
    int pz = zi*1024;
    #pragma unroll
    for (int yr = 0; yr < 10; ++yr) {
      int yi = y0 + yr - 3;
      if ((unsigned)yi >= 32u) continue;  // wave-uniform
      int pr = pz + yi*32;
      float row[10];
      #pragma unroll
      for (int j = 0; j < 10; ++j) {
        int xi = x0 + j - 3;
        row[j] = ((unsigned)xi < 32u) ? xb[(size_t)(pr + xi)*CCH + c] : 0.f;
      }
      #pragma unroll
      for (int dy = 0; dy < 4; ++dy) {
        int ky = yr - dy;
        if (ky < 0 || ky > 6) continue;   // compile-time after unroll
        #pragma unroll
        for (int kx = 0; kx < 7; ++kx) {
          float w = wreg[ky*7 + kx];
          #pragma unroll
          for (int dx = 0; dx < 4; ++dx)
            acc[dy*4 + dx] = fmaf(w, row[kx + dx], acc[dy*4 + dx]);
        }
      }
    }
  }

  // bias + LN stats (reduce over channels = lanes, then across 3 c-groups)
  float bias = dw_b[c];
  float s[16], sq[16];
  #pragma unroll
  for (int m = 0; m < 16; ++m) {
    float y = acc[m] + bias;
    acc[m] = y; s[m] = y; sq[m] = y*y;
  }
  #pragma unroll
  for (int m = 0; m < 16; ++m) {
    #pragma unroll
    for (int off = 1; off < 64; off <<= 1) {
      s[m]  += __shfl_xor(s[m],  off, 64);
      sq[m] += __shfl_xor(sq[m], off, 64);
    }
  }
  __shared__ float lds_s[12][16], lds_q[12][16];
  if (lane == 0) {
    #pragma unroll
    for (int m = 0; m < 16; ++m) { lds_s[wave][m] = s[m]; lds_q[wave][m] = sq[m]; }
  }
  __syncthreads();

  float lnw = ln_w[c], lnb = ln_b[c];
  unsigned short* dst = lnA + (size_t)bid*12288;
  int ks = c >> 5, laneq = (c >> 3) & 3, jb = c & 7;
  #pragma unroll
  for (int m = 0; m < 16; ++m) {
    float st = lds_s[dz][m] + lds_s[dz+4][m] + lds_s[dz+8][m];
    float qt = lds_q[dz][m] + lds_q[dz+4][m] + lds_q[dz+8][m];
    float mu = st * (1.f/192.f);
    float var = qt * (1.f/192.f) - mu*mu;
    float rs = rsqrtf(var + 1e-6f);
    float v = (acc[m] - mu)*rs*lnw + lnb;
    // A-frag position: token m_tok = dz*16+m, channel c
    int elem = ((dz*6 + ks)*64 + laneq*16 + m)*8 + jb;
    dst[elem] = f2bf(v);
  }
}

// ---------------------------------------------------------------------------
// Kernel 4: MLP (bf16 MFMA) per active cell: ln(64x192) @ w1 -> gelu -> @ w2,
// *gamma + b2, store channels-first. Hidden chunked 6x128; h round-trips
// through LDS in A-fragment order (conflict-free b128 reads).
// ---------------------------------------------------------------------------
__global__ __launch_bounds__(256, 2) void mlp_kernel(
    const unsigned short* __restrict__ lnA, const unsigned short* __restrict__ b1f,
    const unsigned short* __restrict__ b2f, const float* __restrict__ b1,
    const float* __restrict__ b2, const float* __restrict__ gamma,
    const int* __restrict__ mask, float* __restrict__ out)
{
  int bid = blockIdx.x;
  if (mask[bid] == 0) return;
  int b = bid >> 9, cell = bid & 511;
  int cz = cell >> 6, cy = (cell >> 3) & 7, cx = cell & 7;
  int z0 = cz*4, y0 = cy*4, x0 = cx*4;
  int tid = threadIdx.x, wave = tid >> 6, lane = tid & 63;
  int lq = lane >> 4, ln15 = lane & 15;

  __shared__ unsigned short hbuf[2][8192];   // 2 x 16 KB, A-frag order

  const unsigned short* Abase = lnA + (size_t)bid*12288;
  bf8v A[4][6];
  #pragma unroll
  for (int mt = 0; mt < 4; ++mt)
    #pragma unroll
    for (int ks = 0; ks < 6; ++ks)
      A[mt][ks] = *(const bf8v*)(Abase + ((mt*6 + ks)*64 + lane)*8);

  f4v acc2[4][3];
  #pragma unroll
  for (int mt = 0; mt < 4; ++mt)
    #pragma unroll
    for (int nt = 0; nt < 3; ++nt)
      acc2[mt][nt] = (f4v){0.f, 0.f, 0.f, 0.f};

  for (int ch = 0; ch < 6; ++ch) {
    // ---- GEMM1: h[:, ch*128 .. +128) ; wave owns ntiles ch*8+wave*2+{0,1}
    f4v acc1[4][2];
    #pragma unroll
    for (int mt = 0; mt < 4; ++mt)
      #pragma unroll
      for (int jj = 0; jj < 2; ++jj)
        acc1[mt][jj] = (f4v){0.f, 0.f, 0.f, 0.f};
    #pragma unroll
    for (int ks = 0; ks < 6; ++ks) {
      #pragma unroll
      for (int jj = 0; jj < 2; ++jj) {
        int nt = ch*8 + wave*2 + jj;
        bf8v Bf = *(const bf8v*)(b1f + ((nt*6 + ks)*64 + lane)*8);
        #pragma unroll
        for (int mt = 0; mt < 4; ++mt)
          acc1[mt][jj] = __builtin_amdgcn_mfma_f32_16x16x32_bf16(A[mt][ks], Bf, acc1[mt][jj], 0, 0, 0);
      }
    }
    // ---- bias + gelu -> hbuf (A2-fragment order; ks2 slot = this wave)
    unsigned short* hb = hbuf[ch & 1];
    #pragma unroll
    for (int jj = 0; jj < 2; ++jj) {
      float b1v = b1[(ch*8 + wave*2 + jj)*16 + ln15];
      int lane_hi = jj*2 + (ln15 >> 3);       // (e%32)/8
      #pragma unroll
      for (int mt = 0; mt < 4; ++mt)
        #pragma unroll
        for (int r = 0; r < 4; ++r) {
          float g = gelu_f(acc1[mt][jj][r] + b1v);
          int elem = ((mt*4 + wave)*64 + lane_hi*16 + (lq*4 + r))*8 + (lane & 7);
          hb[elem] = f2bf(g);
        }
    }
    __syncthreads();
    // ---- GEMM2 partial: out += h_chunk @ w2[ch*128.. , :]
    #pragma unroll
    for (int ks2 = 0; ks2 < 4; ++ks2) {
      bf8v A2[4];
      #pragma unroll
      for (int mt = 0; mt < 4; ++mt)
        A2[mt] = *(const bf8v*)(hb + ((mt*4 + ks2)*64 + lane)*8);
      #pragma unroll
      for (int nt = 0; nt < 3; ++nt) {
        int ntg = wave*3 + nt;
        int ksg = ch*4 + ks2;
        bf8v B2 = *(const bf8v*)(b2f + ((ntg*24 + ksg)*64 + lane)*8);
        #pragma unroll
        for (int mt = 0; mt < 4; ++mt)
          acc2[mt][nt] = __builtin_amdgcn_mfma_f32_16x16x32_bf16(A2[mt], B2, acc2[mt][nt], 0, 0, 0);
      }
    }
  }

  // ---- epilogue: gamma*(acc+b2), store channels-first fp32
  #pragma unroll
  for (int nt = 0; nt < 3; ++nt) {
    int c = (wave*3 + nt)*16 + ln15;
    float gm = gamma[c], bb = b2[c];
    size_t cbase = ((size_t)b*CCH + c)*NPOS;
    #pragma unroll
    for (int mt = 0; mt < 4; ++mt) {
      #pragma unroll
      for (int r = 0; r < 4; ++r) {
        float v = gm*(acc2[mt][nt][r] + bb);
        out[cbase + (z0 + mt)*1024 + (y0 + lq)*32 + x0 + r] = v;
      }
    }
  }
}

// ---------------------------------------------------------------------------
extern "C" void kernel_launch(void* const* d_in, const int* in_sizes, int n_in,
                              void* d_out, int out_size, void* d_ws, size_t ws_size,
                              hipStream_t stream) {
  const float* x     = (const float*)d_in[0];
  const int*   mask  = (const int*)  d_in[1];
  const float* dw_w  = (const float*)d_in[2];
  const float* dw_b  = (const float*)d_in[3];
  const float* ln_w  = (const float*)d_in[4];
  const float* ln_b  = (const float*)d_in[5];
  const float* w1    = (const float*)d_in[6];
  const float* b1    = (const float*)d_in[7];
  const float* w2    = (const float*)d_in[8];
  const float* b2    = (const float*)d_in[9];
  const float* gamma = (const float*)d_in[10];
  float* out = (float*)d_out;
  char* ws = (char*)d_ws;

  float*          xT  = (float*)(ws + WS_XT);
  float*          w_t = (float*)(ws + WS_WT);
  unsigned short* b1f = (unsigned short*)(ws + WS_B1F);
  unsigned short* b2f = (unsigned short*)(ws + WS_B2F);
  unsigned short* lnA = (unsigned short*)(ws + WS_LNA);

  transpose_x_kernel<<<2048, 256, 0, stream>>>(x, xT);
  prep_w_kernel<<<402, 256, 0, stream>>>(dw_w, w1, w2, w_t, b1f, b2f);
  conv_ln_kernel<<<1024, 768, 0, stream>>>(xT, w_t, dw_b, ln_w, ln_b, mask, lnA, out);
  mlp_kernel<<<1024, 256, 0, stream>>>(lnA, b1f, b2f, b1, b2, gamma, mask, out);
}